// Round 13
// baseline (1046.263 us; speedup 1.0000x reference)
//
#include <hip/hip_runtime.h>
#include <hip/hip_bf16.h>

typedef __bf16 bf16_t;
typedef __attribute__((ext_vector_type(8))) __bf16 bf16x8;
typedef __attribute__((ext_vector_type(4))) float f32x4;

constexpr int IN_F  = 4096;
constexpr int OUT_F = 16384;
constexpr int N_TOK = 8192;
constexpr int KSEL  = 8192;
constexpr long A_ELEMS = (long)N_TOK * IN_F;

constexpr int BM = 256, BN = 256, BK = 64;
constexpr int NT = IN_F / BK;        // 64 K-tiles

#define GLOBAL_CAST(p) (const __attribute__((address_space(1))) void*)(p)
#define LDS_CAST(p)    (__attribute__((address_space(3))) void*)(p)

// ---------------------------------------------------------------------------
// Kernel 1: idx[] = positions of mask==1 (ascending) + gather bias (fp32).
// ---------------------------------------------------------------------------
__global__ __launch_bounds__(1024) void build_idx_kernel(
    const int* __restrict__ mask, const float* __restrict__ bias,
    int* __restrict__ idx, float* __restrict__ bsel)
{
    const int t    = threadIdx.x;
    const int lane = t & 63;
    const int wave = t >> 6;
    const int base_i = t * 16;

    int m[16];
    const int4* mp = (const int4*)(mask + base_i);
#pragma unroll
    for (int v = 0; v < 4; ++v) {
        int4 q = mp[v];
        m[v*4+0] = q.x; m[v*4+1] = q.y; m[v*4+2] = q.z; m[v*4+3] = q.w;
    }
    int cnt = 0;
#pragma unroll
    for (int j = 0; j < 16; ++j) cnt += (m[j] != 0) ? 1 : 0;

    int incl = cnt;
#pragma unroll
    for (int d = 1; d < 64; d <<= 1) {
        int o = __shfl_up(incl, (unsigned)d);
        if (lane >= d) incl += o;
    }

    __shared__ int wsum[16];
    __shared__ int wbase[16];
    if (lane == 63) wsum[wave] = incl;
    __syncthreads();
    if (t == 0) {
        int s = 0;
        for (int w = 0; w < 16; ++w) { wbase[w] = s; s += wsum[w]; }
    }
    __syncthreads();

    int p = wbase[wave] + (incl - cnt);
#pragma unroll
    for (int j = 0; j < 16; ++j) {
        if (m[j]) {
            int i = base_i + j;
            idx[p]  = i;
            bsel[p] = bias[i];
            ++p;
        }
    }
}

// ---------------------------------------------------------------------------
// Kernel 2: fp32 -> bf16 convert; A straight, W gathered by idx.
// ---------------------------------------------------------------------------
__global__ __launch_bounds__(256) void convert_kernel(
    const float* __restrict__ A, const float* __restrict__ W,
    const int* __restrict__ idx,
    bf16_t* __restrict__ Ab, bf16_t* __restrict__ Wb)
{
    const long nvecA = A_ELEMS / 8;
    const long total = nvecA * 2;
    const long stride = (long)gridDim.x * blockDim.x;
    for (long v = (long)blockIdx.x * blockDim.x + threadIdx.x; v < total; v += stride) {
        const float4* src;
        bf16_t* dst;
        if (v < nvecA) {
            src = (const float4*)(A + v * 8);
            dst = Ab + v * 8;
        } else {
            long u = v - nvecA;
            int j = (int)(u >> 9);
            int k = (int)(u & 511) * 8;
            src = (const float4*)(W + (long)idx[j] * IN_F + k);
            dst = Wb + u * 8;
        }
        float4 x = src[0], y = src[1];
        bf16x8 o;
        o[0]=(bf16_t)x.x; o[1]=(bf16_t)x.y; o[2]=(bf16_t)x.z; o[3]=(bf16_t)x.w;
        o[4]=(bf16_t)y.x; o[5]=(bf16_t)y.y; o[6]=(bf16_t)y.z; o[7]=(bf16_t)y.w;
        *(bf16x8*)dst = o;
    }
}

// ---------------------------------------------------------------------------
// Kernel 3: 8-phase 256x256 BK=64 + ONE-PHASE-DEEP REGISTER PIPELINE:
// phase p's MFMA overlaps issuing phase p+1's ds_reads (ping-pong frag sets
// afA/afB, bg0/bg1). 8 barriers/iter (1 per phase). Counted drains moved to
// ph3/ph7 (vmcnt(4)) so the newly drained tile is published by a barrier
// BEFORE its first reads are issued one phase early (formal chain verified).
// Stage slots unchanged: ph3:B(t+2)->Bs0, ph4:A(t+2)->As0, ph7:B(u+2)->Bs1,
// ph8:A(u+2)->As1. Flat-LDS precomputed read bases (r12). XOR slot swizzle
// via pre-swizzled global source. Tail: vmcnt(0) at ph3, no stages/issues.
// ---------------------------------------------------------------------------
__global__ __launch_bounds__(512, 2) void gemm8p_kernel(
    const bf16_t* __restrict__ A, const bf16_t* __restrict__ B,
    const float* __restrict__ bsel, float* __restrict__ C)
{
    __shared__ __attribute__((aligned(16))) char lds[131072];

    const int tid  = threadIdx.x;
    const int w    = tid >> 6;
    const int lane = tid & 63;
    const int wr   = w >> 2;            // 0..1 -> 128-row A strip (= A half)
    const int wc   = w & 3;             // 0..3 -> 64-col B strip (half = wc>>1)

    // XCD swizzle: n-panel chunk per XCD, m fastest (1024 % 8 == 0)
    const int bid = blockIdx.x;
    const int swz = (bid & 7) * 128 + (bid >> 3);
    const int m0 = (swz & 31) * BM;
    const int n0 = (swz >> 5) * BN;

    // staging source (inverse XOR slot swizzle; LDS dest linear)
    const int pr  = lane >> 3;
    const int csw = ((lane & 7) ^ pr) * 8;
    const bf16_t* aSrc[2][2];
    const bf16_t* bSrc[2][2];
#pragma unroll
    for (int h = 0; h < 2; ++h)
#pragma unroll
        for (int j = 0; j < 2; ++j) {
            const int row = h * 128 + (w * 2 + j) * 8 + pr;
            aSrc[h][j] = A + (long)(m0 + row) * IN_F + csw;
            bSrc[h][j] = B + (long)(n0 + row) * IN_F + csw;
        }

// LDS bytes: buf*65536 + {A: h*16384 | B: 32768 + h*16384} + w*2048 (+1024)
#define ST_A(buf, h, tl) do {                                                  \
    __builtin_amdgcn_global_load_lds(GLOBAL_CAST(aSrc[h][0] + (long)(tl)*BK),  \
        LDS_CAST(lds + (buf)*65536 + (h)*16384 + w*2048), 16, 0, 0);           \
    __builtin_amdgcn_global_load_lds(GLOBAL_CAST(aSrc[h][1] + (long)(tl)*BK),  \
        LDS_CAST(lds + (buf)*65536 + (h)*16384 + w*2048 + 1024), 16, 0, 0);    \
} while (0)
#define ST_B(buf, h, tl) do {                                                  \
    __builtin_amdgcn_global_load_lds(GLOBAL_CAST(bSrc[h][0] + (long)(tl)*BK),  \
        LDS_CAST(lds + (buf)*65536 + 32768 + (h)*16384 + w*2048), 16, 0, 0);   \
    __builtin_amdgcn_global_load_lds(GLOBAL_CAST(bSrc[h][1] + (long)(tl)*BK),  \
        LDS_CAST(lds + (buf)*65536 + 32768 + (h)*16384 + w*2048 + 1024),       \
        16, 0, 0);                                                             \
} while (0)

    f32x4 acc[8][4];
#pragma unroll
    for (int m = 0; m < 8; ++m)
#pragma unroll
        for (int n = 0; n < 4; ++n)
#pragma unroll
            for (int j = 0; j < 4; ++j) acc[m][n][j] = 0.f;

    const int fr    = lane & 15;
    const int kslot = lane >> 4;
    const int sp0b = ((kslot       ^ (fr & 7)) << 4);
    const int sp1b = (((4 + kslot) ^ (fr & 7)) << 4);

    // loop-invariant per-thread LDS read bases (bytes)
    const int a0s0 = wr * 16384 + fr * 128 + sp0b;
    const int a0s1 = wr * 16384 + fr * 128 + sp1b;
    const int a1s0 = a0s0 + 65536;
    const int a1s1 = a0s1 + 65536;
    const int bb   = 32768 + (wc >> 1) * 16384 + ((wc & 1) * 64 + fr) * 128;
    const int b0s0 = bb + sp0b;
    const int b0s1 = bb + sp1b;
    const int b1s0 = b0s0 + 65536;
    const int b1s1 = b0s1 + 65536;

    // ping-pong fragment sets
    bf16x8 afA[4][2], afB[4][2], bg0[2][2], bg1[2][2];

#define RDA_TO(DST, s0, s1, mq) do {                                           \
    _Pragma("unroll") for (int mm = 0; mm < 4; ++mm) {                         \
        DST[mm][0] = *(const bf16x8*)(lds + (s0) + (mq)*8192 + mm*2048);       \
        DST[mm][1] = *(const bf16x8*)(lds + (s1) + (mq)*8192 + mm*2048);       \
    } } while (0)
#define RDB_TO(DST, s0, s1, nh) do {                                           \
    _Pragma("unroll") for (int nn = 0; nn < 2; ++nn) {                         \
        DST[nn][0] = *(const bf16x8*)(lds + (s0) + ((nh)*2+nn)*2048);          \
        DST[nn][1] = *(const bf16x8*)(lds + (s1) + ((nh)*2+nn)*2048);          \
    } } while (0)
#define MFMAP(AF, BG, mq, nh) do {                                             \
    __builtin_amdgcn_s_setprio(1);                                             \
    _Pragma("unroll") for (int mm = 0; mm < 4; ++mm)                           \
    _Pragma("unroll") for (int nn = 0; nn < 2; ++nn) {                         \
        const int m = (mq) * 4 + mm, n = (nh) * 2 + nn;                        \
        acc[m][n] = __builtin_amdgcn_mfma_f32_16x16x32_bf16(                   \
            AF[mm][0], BG[nn][0], acc[m][n], 0, 0, 0);                         \
        acc[m][n] = __builtin_amdgcn_mfma_f32_16x16x32_bf16(                   \
            AF[mm][1], BG[nn][1], acc[m][n], 0, 0, 0);                         \
    }                                                                          \
    __builtin_amdgcn_s_setprio(0); } while (0)
#define BAR()    __builtin_amdgcn_s_barrier()
#define LGKM0()  asm volatile("s_waitcnt lgkmcnt(0)" ::: "memory")
#define VMC4()   asm volatile("s_waitcnt vmcnt(4)" ::: "memory")
#define VMC8()   asm volatile("s_waitcnt vmcnt(8)" ::: "memory")
#define VMC0()   asm volatile("s_waitcnt vmcnt(0)" ::: "memory")

    // prologue: stage tiles 0 (first) and 1; drain tile 0 (own) ; publish; 
    // then issue ph1's reads (formally after barrier postdating all drains)
    ST_B(0, 0, 0); ST_B(0, 1, 0); ST_A(0, 0, 0); ST_A(0, 1, 0);
    ST_B(1, 0, 1); ST_B(1, 1, 1); ST_A(1, 0, 1); ST_A(1, 1, 1);
    VMC8(); BAR();
    RDA_TO(afA, a0s0, a0s1, 0);
    RDB_TO(bg0, b0s0, b0s1, 0);

    for (int I = 0; I < NT / 2; ++I) {
        const int t = 2 * I, u = t + 1;          // t -> buf0, u -> buf1
        const bool s2 = (I < NT / 2 - 1);

        // ph1: wait(afA mq0-t, bg0 nh0-t); issue bg1<-nh1-t; MFMA(mq0,nh0)
        LGKM0();
        RDB_TO(bg1, b0s0, b0s1, 1);
        MFMAP(afA, bg0, 0, 0);
        BAR();

        // ph2: wait(bg1); issue afB<-mq1-t; MFMA(mq0,nh1)
        LGKM0();
        RDA_TO(afB, a0s0, a0s1, 1);
        MFMAP(afA, bg1, 0, 1);
        BAR();

        // ph3: stage Bs0<-B(t+2); wait(afB); MFMA(mq1,nh0);
        //      counted drain publishes tile u for ph4's read-issues
        if (s2) { ST_B(0, 0, t + 2); ST_B(0, 1, t + 2); }
        LGKM0();
        MFMAP(afB, bg0, 1, 0);
        if (s2) VMC4(); else VMC0();
        BAR();

        // ph4: stage As0<-A(t+2); issue afA<-mq0-u, bg0<-nh0-u (tile u
        //      published at ph3's vmcnt+barrier); MFMA(mq1,nh1)
        if (s2) { ST_A(0, 0, t + 2); ST_A(0, 1, t + 2); }
        RDA_TO(afA, a1s0, a1s1, 0);
        RDB_TO(bg0, b1s0, b1s1, 0);
        MFMAP(afB, bg1, 1, 1);
        BAR();

        // ph5: wait; issue bg1<-nh1-u; MFMA(mq0,nh0) of u
        LGKM0();
        RDB_TO(bg1, b1s0, b1s1, 1);
        MFMAP(afA, bg0, 0, 0);
        BAR();

        // ph6: wait; issue afB<-mq1-u; MFMA(mq0,nh1)
        LGKM0();
        RDA_TO(afB, a1s0, a1s1, 1);
        MFMAP(afA, bg1, 0, 1);
        BAR();

        // ph7: stage Bs1<-B(u+2); wait(afB); MFMA(mq1,nh0);
        //      counted drain publishes tile t+2 for ph8's read-issues
        if (s2) { ST_B(1, 0, u + 2); ST_B(1, 1, u + 2); }
        LGKM0();
        MFMAP(afB, bg0, 1, 0);
        if (s2) VMC4();
        BAR();

        // ph8: stage As1<-A(u+2); issue next-iter ph1 reads (tile t+2,
        //      published at ph7); MFMA(mq1,nh1)
        if (s2) {
            ST_A(1, 0, u + 2); ST_A(1, 1, u + 2);
            RDA_TO(afA, a0s0, a0s1, 0);
            RDB_TO(bg0, b0s0, b0s1, 0);
        }
        MFMAP(afB, bg1, 1, 1);
        BAR();
    }
    VMC0();

#undef ST_A
#undef ST_B
#undef RDA_TO
#undef RDB_TO
#undef MFMAP
#undef BAR
#undef LGKM0
#undef VMC4
#undef VMC8
#undef VMC0

    // epilogue: +bias, fp32 store (mapping verified rounds 3-12)
    float b4[4];
#pragma unroll
    for (int n = 0; n < 4; ++n) b4[n] = bsel[n0 + wc * 64 + n * 16 + fr];

    const int rbase = m0 + wr * 128 + kslot * 4;
#pragma unroll
    for (int m = 0; m < 8; ++m)
#pragma unroll
        for (int n = 0; n < 4; ++n) {
            const int col = n0 + wc * 64 + n * 16 + fr;
#pragma unroll
            for (int j = 0; j < 4; ++j)
                C[(long)(rbase + m * 16 + j) * KSEL + col] = acc[m][n][j] + b4[n];
        }
}

// ---------------------------------------------------------------------------
// Fallback (ws too small): fp32-staged m97-structure GEMM (known-correct).
// ---------------------------------------------------------------------------
__global__ __launch_bounds__(256) void gemm_f32staged_kernel(
    const float* __restrict__ A, const float* __restrict__ W,
    const int* __restrict__ idx, const float* __restrict__ bsel,
    float* __restrict__ C)
{
    constexpr int FBM = 128, FBN = 128, BK2 = 32;
    __shared__ __attribute__((aligned(16))) float Asf[FBM * BK2];
    __shared__ __attribute__((aligned(16))) float Bsf[FBN * BK2];

    const int tid  = threadIdx.x;
    const int wave = tid >> 6;
    const int lane = tid & 63;
    const int wrf  = wave >> 1;
    const int wcf  = wave & 1;

    const int m0 = blockIdx.x * FBM;
    const int n0 = blockIdx.y * FBN;

    const int srow = lane >> 3;
    const int scol = (lane & 7) * 4;

    const float* aptr[4];
    const float* bptr[4];
#pragma unroll
    for (int i = 0; i < 4; ++i) {
        aptr[i] = A + (long)(m0 + wave * 32 + i * 8 + srow) * IN_F + scol;
        const int br = idx[n0 + wave * 32 + i * 8 + srow];
        bptr[i] = W + (long)br * IN_F + scol;
    }

    f32x4 acc[4][4];
#pragma unroll
    for (int m = 0; m < 4; ++m)
#pragma unroll
        for (int n = 0; n < 4; ++n)
#pragma unroll
            for (int j = 0; j < 4; ++j) acc[m][n][j] = 0.f;

    const int fr = lane & 15;
    const int fk = (lane >> 4) * 8;

    for (int k0 = 0; k0 < IN_F; k0 += BK2) {
#pragma unroll
        for (int i = 0; i < 4; ++i) {
            __builtin_amdgcn_global_load_lds(GLOBAL_CAST(aptr[i] + k0),
                LDS_CAST(&Asf[(wave * 32 + i * 8) * BK2]), 16, 0, 0);
            __builtin_amdgcn_global_load_lds(GLOBAL_CAST(bptr[i] + k0),
                LDS_CAST(&Bsf[(wave * 32 + i * 8) * BK2]), 16, 0, 0);
        }
        __syncthreads();

        bf16x8 af[4], bg[4];
#pragma unroll
        for (int m = 0; m < 4; ++m) {
            const float* p = &Asf[(wrf * 64 + m * 16 + fr) * BK2 + fk];
            f32x4 x = *(const f32x4*)p, y = *(const f32x4*)(p + 4);
#pragma unroll
            for (int j = 0; j < 4; ++j) { af[m][j] = (bf16_t)x[j]; af[m][4+j] = (bf16_t)y[j]; }
        }
#pragma unroll
        for (int n = 0; n < 4; ++n) {
            const float* p = &Bsf[(wcf * 64 + n * 16 + fr) * BK2 + fk];
            f32x4 x = *(const f32x4*)p, y = *(const f32x4*)(p + 4);
#pragma unroll
            for (int j = 0; j < 4; ++j) { bg[n][j] = (bf16_t)x[j]; bg[n][4+j] = (bf16_t)y[j]; }
        }
#pragma unroll
        for (int m = 0; m < 4; ++m)
#pragma unroll
            for (int n = 0; n < 4; ++n)
                acc[m][n] = __builtin_amdgcn_mfma_f32_16x16x32_bf16(
                    af[m], bg[n], acc[m][n], 0, 0, 0);
        __syncthreads();
    }

    float b4[4];
#pragma unroll
    for (int n = 0; n < 4; ++n) b4[n] = bsel[n0 + wcf * 64 + n * 16 + fr];

    const int rbase = m0 + wrf * 64 + (lane >> 4) * 4;
#pragma unroll
    for (int m = 0; m < 4; ++m)
#pragma unroll
        for (int n = 0; n < 4; ++n) {
            const int col = n0 + wcf * 64 + n * 16 + fr;
#pragma unroll
            for (int j = 0; j < 4; ++j)
                C[(long)(rbase + m * 16 + j) * KSEL + col] = acc[m][n][j] + b4[n];
        }
}

// ---------------------------------------------------------------------------
extern "C" void kernel_launch(void* const* d_in, const int* in_sizes, int n_in,
                              void* d_out, int out_size, void* d_ws, size_t ws_size,
                              hipStream_t stream)
{
    const float* data   = (const float*)d_in[0];
    const float* weight = (const float*)d_in[1];
    const float* bias   = (const float*)d_in[2];
    const int*   mask   = (const int*)d_in[3];
    float*       out    = (float*)d_out;

    char* ws = (char*)d_ws;
    int*   idx  = (int*)ws;
    float* bsel = (float*)(ws + (KSEL * 4));
    bf16_t* Ab  = (bf16_t*)(ws + (KSEL * 8));
    bf16_t* Wb  = Ab + A_ELEMS;

    const size_t NEED = (size_t)KSEL * 8 + (size_t)A_ELEMS * 2 * 2;

    build_idx_kernel<<<1, 1024, 0, stream>>>(mask, bias, idx, bsel);

    if (ws_size >= NEED) {
        convert_kernel<<<2048, 256, 0, stream>>>(data, weight, idx, Ab, Wb);
        gemm8p_kernel<<<1024, 512, 0, stream>>>(Ab, Wb, bsel, out);
    } else {
        dim3 grid(N_TOK / 128, KSEL / 128);
        gemm_f32staged_kernel<<<grid, 256, 0, stream>>>(data, weight, idx, bsel, out);
    }
}

// Round 14
// 688.479 us; speedup vs baseline: 1.5197x; 1.5197x over previous
//
#include <hip/hip_runtime.h>
#include <hip/hip_bf16.h>

typedef __bf16 bf16_t;
typedef __attribute__((ext_vector_type(8))) __bf16 bf16x8;
typedef __attribute__((ext_vector_type(4))) float f32x4;

constexpr int IN_F  = 4096;
constexpr int OUT_F = 16384;
constexpr int N_TOK = 8192;
constexpr int KSEL  = 8192;
constexpr long A_ELEMS = (long)N_TOK * IN_F;

constexpr int BM = 256, BN = 256, BK = 64;
constexpr int NT = IN_F / BK;        // 64 K-tiles

#define GLOBAL_CAST(p) (const __attribute__((address_space(1))) void*)(p)
#define LDS_CAST(p)    (__attribute__((address_space(3))) void*)(p)

// ---------------------------------------------------------------------------
// Kernel 1: idx[] = positions of mask==1 (ascending) + gather bias (fp32).
// ---------------------------------------------------------------------------
__global__ __launch_bounds__(1024) void build_idx_kernel(
    const int* __restrict__ mask, const float* __restrict__ bias,
    int* __restrict__ idx, float* __restrict__ bsel)
{
    const int t    = threadIdx.x;
    const int lane = t & 63;
    const int wave = t >> 6;
    const int base_i = t * 16;

    int m[16];
    const int4* mp = (const int4*)(mask + base_i);
#pragma unroll
    for (int v = 0; v < 4; ++v) {
        int4 q = mp[v];
        m[v*4+0] = q.x; m[v*4+1] = q.y; m[v*4+2] = q.z; m[v*4+3] = q.w;
    }
    int cnt = 0;
#pragma unroll
    for (int j = 0; j < 16; ++j) cnt += (m[j] != 0) ? 1 : 0;

    int incl = cnt;
#pragma unroll
    for (int d = 1; d < 64; d <<= 1) {
        int o = __shfl_up(incl, (unsigned)d);
        if (lane >= d) incl += o;
    }

    __shared__ int wsum[16];
    __shared__ int wbase[16];
    if (lane == 63) wsum[wave] = incl;
    __syncthreads();
    if (t == 0) {
        int s = 0;
        for (int w = 0; w < 16; ++w) { wbase[w] = s; s += wsum[w]; }
    }
    __syncthreads();

    int p = wbase[wave] + (incl - cnt);
#pragma unroll
    for (int j = 0; j < 16; ++j) {
        if (m[j]) {
            int i = base_i + j;
            idx[p]  = i;
            bsel[p] = bias[i];
            ++p;
        }
    }
}

// ---------------------------------------------------------------------------
// Kernel 2: fp32 -> bf16 convert; A straight, W gathered by idx.
// 4096 blocks: exactly one 8-elem vector per thread (33.5M vecs x2 /
// (4096*256) = 2 -> two per thread, no loop retest cost worth noting).
// ---------------------------------------------------------------------------
__global__ __launch_bounds__(256) void convert_kernel(
    const float* __restrict__ A, const float* __restrict__ W,
    const int* __restrict__ idx,
    bf16_t* __restrict__ Ab, bf16_t* __restrict__ Wb)
{
    const long nvecA = A_ELEMS / 8;
    const long total = nvecA * 2;
    const long stride = (long)gridDim.x * blockDim.x;
    for (long v = (long)blockIdx.x * blockDim.x + threadIdx.x; v < total; v += stride) {
        const float4* src;
        bf16_t* dst;
        if (v < nvecA) {
            src = (const float4*)(A + v * 8);
            dst = Ab + v * 8;
        } else {
            long u = v - nvecA;
            int j = (int)(u >> 9);
            int k = (int)(u & 511) * 8;
            src = (const float4*)(W + (long)idx[j] * IN_F + k);
            dst = Wb + u * 8;
        }
        float4 x = src[0], y = src[1];
        bf16x8 o;
        o[0]=(bf16_t)x.x; o[1]=(bf16_t)x.y; o[2]=(bf16_t)x.z; o[3]=(bf16_t)x.w;
        o[4]=(bf16_t)y.x; o[5]=(bf16_t)y.y; o[6]=(bf16_t)y.z; o[7]=(bf16_t)y.w;
        *(bf16x8*)dst = o;
    }
}

// ---------------------------------------------------------------------------
// Kernel 3 (= round-12, best measured: 582us GEMM / 945 TF):
// r8 8-phase 256x256 BK=64 schedule + PRECOMPUTED LDS read bases (flat
// 128KB LDS; per-buf {A-h0 @0, A-h1 @16K, B-h0 @32K, B-h1 @48K}, buf1 @
// +64K; all in-loop ds_reads are base + compile-time-const -> offset imm).
// Stagger: ph3 stages B(t+2), ph4 A(t+2), ph7 B(u+2), ph8 A(u+2);
// vmcnt(8) at ph4/ph8 (tail: vmcnt(0) at ph4). XOR slot swizzle via
// pre-swizzled global source (conflicts=0 measured). Single frag set —
// ping-pong variant spills (r13: +320MB scratch traffic, -39% perf).
// ---------------------------------------------------------------------------
__global__ __launch_bounds__(512, 2) void gemm8p_kernel(
    const bf16_t* __restrict__ A, const bf16_t* __restrict__ B,
    const float* __restrict__ bsel, float* __restrict__ C)
{
    __shared__ __attribute__((aligned(16))) char lds[131072];

    const int tid  = threadIdx.x;
    const int w    = tid >> 6;
    const int lane = tid & 63;
    const int wr   = w >> 2;            // 0..1 -> 128-row A strip (= A half)
    const int wc   = w & 3;             // 0..3 -> 64-col B strip (half = wc>>1)

    // XCD swizzle: n-panel chunk per XCD, m fastest (1024 % 8 == 0)
    const int bid = blockIdx.x;
    const int swz = (bid & 7) * 128 + (bid >> 3);
    const int m0 = (swz & 31) * BM;
    const int n0 = (swz >> 5) * BN;

    // staging source (inverse XOR slot swizzle; LDS dest linear)
    const int pr  = lane >> 3;                  // phys row within 8-row load
    const int csw = ((lane & 7) ^ pr) * 8;      // logical col for phys slot
    const bf16_t* aSrc[2][2];
    const bf16_t* bSrc[2][2];
#pragma unroll
    for (int h = 0; h < 2; ++h)
#pragma unroll
        for (int j = 0; j < 2; ++j) {
            const int row = h * 128 + (w * 2 + j) * 8 + pr;
            aSrc[h][j] = A + (long)(m0 + row) * IN_F + csw;
            bSrc[h][j] = B + (long)(n0 + row) * IN_F + csw;
        }

// LDS byte offsets: buf*65536 + {A: h*16384 | B: 32768 + h*16384} + sub*1024
#define ST_A(buf, h, tl) do {                                                  \
    __builtin_amdgcn_global_load_lds(GLOBAL_CAST(aSrc[h][0] + (long)(tl)*BK),  \
        LDS_CAST(lds + (buf)*65536 + (h)*16384 + w*2048), 16, 0, 0);           \
    __builtin_amdgcn_global_load_lds(GLOBAL_CAST(aSrc[h][1] + (long)(tl)*BK),  \
        LDS_CAST(lds + (buf)*65536 + (h)*16384 + w*2048 + 1024), 16, 0, 0);    \
} while (0)
#define ST_B(buf, h, tl) do {                                                  \
    __builtin_amdgcn_global_load_lds(GLOBAL_CAST(bSrc[h][0] + (long)(tl)*BK),  \
        LDS_CAST(lds + (buf)*65536 + 32768 + (h)*16384 + w*2048), 16, 0, 0);   \
    __builtin_amdgcn_global_load_lds(GLOBAL_CAST(bSrc[h][1] + (long)(tl)*BK),  \
        LDS_CAST(lds + (buf)*65536 + 32768 + (h)*16384 + w*2048 + 1024),       \
        16, 0, 0);                                                             \
} while (0)

    f32x4 acc[8][4];
#pragma unroll
    for (int m = 0; m < 8; ++m)
#pragma unroll
        for (int n = 0; n < 4; ++n)
#pragma unroll
            for (int j = 0; j < 4; ++j) acc[m][n][j] = 0.f;

    const int fr    = lane & 15;
    const int kslot = lane >> 4;
    // swizzled slot BYTE offsets for kk=0 / kk=32
    const int sp0b = ((kslot       ^ (fr & 7)) << 4);
    const int sp1b = (((4 + kslot) ^ (fr & 7)) << 4);

    // precomputed per-thread read bases (bytes into lds) — loop-invariant
    const int a0s0 = wr * 16384 + fr * 128 + sp0b;            // A, buf0, k-half0
    const int a0s1 = wr * 16384 + fr * 128 + sp1b;
    const int a1s0 = a0s0 + 65536;
    const int a1s1 = a0s1 + 65536;
    const int bbase = 32768 + (wc >> 1) * 16384 + ((wc & 1) * 64 + fr) * 128;
    const int b0s0 = bbase + sp0b;
    const int b0s1 = bbase + sp1b;
    const int b1s0 = b0s0 + 65536;
    const int b1s1 = b0s1 + 65536;

    bf16x8 af[4][2], bg[4][2];

// reads: base + const imm only (mq*8192 + mm*2048 / (nh*2+nn)*2048)
#define RDA(s0, s1, mq) do {                                                   \
    _Pragma("unroll") for (int mm = 0; mm < 4; ++mm) {                         \
        af[mm][0] = *(const bf16x8*)(lds + (s0) + (mq)*8192 + mm*2048);        \
        af[mm][1] = *(const bf16x8*)(lds + (s1) + (mq)*8192 + mm*2048);        \
    } } while (0)
#define RDB(s0, s1, nh) do {                                                   \
    _Pragma("unroll") for (int nn = 0; nn < 2; ++nn) {                         \
        bg[(nh)*2+nn][0] = *(const bf16x8*)(lds + (s0) + ((nh)*2+nn)*2048);    \
        bg[(nh)*2+nn][1] = *(const bf16x8*)(lds + (s1) + ((nh)*2+nn)*2048);    \
    } } while (0)
#define MFMAQ(mq, nh) do {                                                     \
    __builtin_amdgcn_s_setprio(1);                                             \
    _Pragma("unroll") for (int mm = 0; mm < 4; ++mm)                           \
    _Pragma("unroll") for (int nn = 0; nn < 2; ++nn) {                         \
        const int m = (mq) * 4 + mm, n = (nh) * 2 + nn;                        \
        acc[m][n] = __builtin_amdgcn_mfma_f32_16x16x32_bf16(                   \
            af[mm][0], bg[n][0], acc[m][n], 0, 0, 0);                          \
        acc[m][n] = __builtin_amdgcn_mfma_f32_16x16x32_bf16(                   \
            af[mm][1], bg[n][1], acc[m][n], 0, 0, 0);                          \
    }                                                                          \
    __builtin_amdgcn_s_setprio(0); } while (0)
#define BAR()    __builtin_amdgcn_s_barrier()
#define LGKM0()  asm volatile("s_waitcnt lgkmcnt(0)" ::: "memory")
#define LGKMH()  asm volatile("s_waitcnt lgkmcnt(8)" ::: "memory")
#define VMC8()   asm volatile("s_waitcnt vmcnt(8)" ::: "memory")
#define VMC0()   asm volatile("s_waitcnt vmcnt(0)" ::: "memory")

    // prologue: stage tiles 0 and 1 fully (16 loads); drain tile 0, keep 1
    ST_A(0, 0, 0); ST_A(0, 1, 0); ST_B(0, 0, 0); ST_B(0, 1, 0);
    ST_A(1, 0, 1); ST_A(1, 1, 1); ST_B(1, 0, 1); ST_B(1, 1, 1);
    VMC8(); BAR();

    for (int I = 0; I < NT / 2; ++I) {
        const int t = 2 * I, u = t + 1;          // t -> buf0, u -> buf1
        const bool s2 = (I < NT / 2 - 1);

        // ph1 (t,mq0,nh0): 12 ds_read
        RDA(a0s0, a0s1, 0); RDB(b0s0, b0s1, 0);
        LGKMH(); BAR(); LGKM0(); MFMAQ(0, 0); BAR();
        // ph2 (t,mq0,nh1): 4 ds_read  [last read of B(t)]
        RDB(b0s0, b0s1, 1);
        BAR(); LGKM0(); MFMAQ(0, 1); BAR();
        // ph3 (t,mq1,nh0): 8 ds_read [last read of A(t)] + stage B(t+2)
        RDA(a0s0, a0s1, 1);
        if (s2) { ST_B(0, 0, t + 2); ST_B(0, 1, t + 2); }
        BAR(); LGKM0(); MFMAQ(1, 0); BAR();
        // ph4 (t,mq1,nh1): stage A(t+2); boundary wait -> tile t+1 landed
        if (s2) { ST_A(0, 0, t + 2); ST_A(0, 1, t + 2); }
        BAR(); MFMAQ(1, 1); if (s2) VMC8(); else VMC0(); BAR();
        // ph5 (u,mq0,nh0): 12 ds_read
        RDA(a1s0, a1s1, 0); RDB(b1s0, b1s1, 0);
        LGKMH(); BAR(); LGKM0(); MFMAQ(0, 0); BAR();
        // ph6 (u,mq0,nh1): 4 ds_read  [last read of B(u)]
        RDB(b1s0, b1s1, 1);
        BAR(); LGKM0(); MFMAQ(0, 1); BAR();
        // ph7 (u,mq1,nh0): 8 ds_read [last read of A(u)] + stage B(u+2)
        RDA(a1s0, a1s1, 1);
        if (s2) { ST_B(1, 0, u + 2); ST_B(1, 1, u + 2); }
        BAR(); LGKM0(); MFMAQ(1, 0); BAR();
        // ph8 (u,mq1,nh1): stage A(u+2); boundary wait -> tile t+2 landed
        if (s2) { ST_A(1, 0, u + 2); ST_A(1, 1, u + 2); }
        BAR(); MFMAQ(1, 1); if (s2) VMC8(); else VMC0(); BAR();
    }
    VMC0();

#undef ST_A
#undef ST_B
#undef RDA
#undef RDB
#undef MFMAQ
#undef BAR
#undef LGKM0
#undef LGKMH
#undef VMC8
#undef VMC0

    // epilogue: +bias, fp32 store (mapping verified rounds 3-12)
    float b4[4];
#pragma unroll
    for (int n = 0; n < 4; ++n) b4[n] = bsel[n0 + wc * 64 + n * 16 + fr];

    const int rbase = m0 + wr * 128 + kslot * 4;
#pragma unroll
    for (int m = 0; m < 8; ++m)
#pragma unroll
        for (int n = 0; n < 4; ++n) {
            const int col = n0 + wc * 64 + n * 16 + fr;
#pragma unroll
            for (int j = 0; j < 4; ++j)
                C[(long)(rbase + m * 16 + j) * KSEL + col] = acc[m][n][j] + b4[n];
        }
}

// ---------------------------------------------------------------------------
// Fallback (ws too small): fp32-staged m97-structure GEMM (known-correct).
// ---------------------------------------------------------------------------
__global__ __launch_bounds__(256) void gemm_f32staged_kernel(
    const float* __restrict__ A, const float* __restrict__ W,
    const int* __restrict__ idx, const float* __restrict__ bsel,
    float* __restrict__ C)
{
    constexpr int FBM = 128, FBN = 128, BK2 = 32;
    __shared__ __attribute__((aligned(16))) float Asf[FBM * BK2];
    __shared__ __attribute__((aligned(16))) float Bsf[FBN * BK2];

    const int tid  = threadIdx.x;
    const int wave = tid >> 6;
    const int lane = tid & 63;
    const int wrf  = wave >> 1;
    const int wcf  = wave & 1;

    const int m0 = blockIdx.x * FBM;
    const int n0 = blockIdx.y * FBN;

    const int srow = lane >> 3;
    const int scol = (lane & 7) * 4;

    const float* aptr[4];
    const float* bptr[4];
#pragma unroll
    for (int i = 0; i < 4; ++i) {
        aptr[i] = A + (long)(m0 + wave * 32 + i * 8 + srow) * IN_F + scol;
        const int br = idx[n0 + wave * 32 + i * 8 + srow];
        bptr[i] = W + (long)br * IN_F + scol;
    }

    f32x4 acc[4][4];
#pragma unroll
    for (int m = 0; m < 4; ++m)
#pragma unroll
        for (int n = 0; n < 4; ++n)
#pragma unroll
            for (int j = 0; j < 4; ++j) acc[m][n][j] = 0.f;

    const int fr = lane & 15;
    const int fk = (lane >> 4) * 8;

    for (int k0 = 0; k0 < IN_F; k0 += BK2) {
#pragma unroll
        for (int i = 0; i < 4; ++i) {
            __builtin_amdgcn_global_load_lds(GLOBAL_CAST(aptr[i] + k0),
                LDS_CAST(&Asf[(wave * 32 + i * 8) * BK2]), 16, 0, 0);
            __builtin_amdgcn_global_load_lds(GLOBAL_CAST(bptr[i] + k0),
                LDS_CAST(&Bsf[(wave * 32 + i * 8) * BK2]), 16, 0, 0);
        }
        __syncthreads();

        bf16x8 af[4], bg[4];
#pragma unroll
        for (int m = 0; m < 4; ++m) {
            const float* p = &Asf[(wrf * 64 + m * 16 + fr) * BK2 + fk];
            f32x4 x = *(const f32x4*)p, y = *(const f32x4*)(p + 4);
#pragma unroll
            for (int j = 0; j < 4; ++j) { af[m][j] = (bf16_t)x[j]; af[m][4+j] = (bf16_t)y[j]; }
        }
#pragma unroll
        for (int n = 0; n < 4; ++n) {
            const float* p = &Bsf[(wcf * 64 + n * 16 + fr) * BK2 + fk];
            f32x4 x = *(const f32x4*)p, y = *(const f32x4*)(p + 4);
#pragma unroll
            for (int j = 0; j < 4; ++j) { bg[n][j] = (bf16_t)x[j]; bg[n][4+j] = (bf16_t)y[j]; }
        }
#pragma unroll
        for (int m = 0; m < 4; ++m)
#pragma unroll
            for (int n = 0; n < 4; ++n)
                acc[m][n] = __builtin_amdgcn_mfma_f32_16x16x32_bf16(
                    af[m], bg[n], acc[m][n], 0, 0, 0);
        __syncthreads();
    }

    float b4[4];
#pragma unroll
    for (int n = 0; n < 4; ++n) b4[n] = bsel[n0 + wcf * 64 + n * 16 + fr];

    const int rbase = m0 + wrf * 64 + (lane >> 4) * 4;
#pragma unroll
    for (int m = 0; m < 4; ++m)
#pragma unroll
        for (int n = 0; n < 4; ++n) {
            const int col = n0 + wcf * 64 + n * 16 + fr;
#pragma unroll
            for (int j = 0; j < 4; ++j)
                C[(long)(rbase + m * 16 + j) * KSEL + col] = acc[m][n][j] + b4[n];
        }
}

// ---------------------------------------------------------------------------
extern "C" void kernel_launch(void* const* d_in, const int* in_sizes, int n_in,
                              void* d_out, int out_size, void* d_ws, size_t ws_size,
                              hipStream_t stream)
{
    const float* data   = (const float*)d_in[0];
    const float* weight = (const float*)d_in[1];
    const float* bias   = (const float*)d_in[2];
    const int*   mask   = (const int*)d_in[3];
    float*       out    = (float*)d_out;

    char* ws = (char*)d_ws;
    int*   idx  = (int*)ws;
    float* bsel = (float*)(ws + (KSEL * 4));
    bf16_t* Ab  = (bf16_t*)(ws + (KSEL * 8));
    bf16_t* Wb  = Ab + A_ELEMS;

    const size_t NEED = (size_t)KSEL * 8 + (size_t)A_ELEMS * 2 * 2;

    build_idx_kernel<<<1, 1024, 0, stream>>>(mask, bias, idx, bsel);

    if (ws_size >= NEED) {
        convert_kernel<<<4096, 256, 0, stream>>>(data, weight, idx, Ab, Wb);
        gemm8p_kernel<<<1024, 512, 0, stream>>>(Ab, Wb, bsel, out);
    } else {
        dim3 grid(N_TOK / 128, KSEL / 128);
        gemm_f32staged_kernel<<<grid, 256, 0, stream>>>(data, weight, idx, bsel, out);
    }
}